// Round 2
// baseline (364.356 us; speedup 1.0000x reference)
//
#include <hip/hip_runtime.h>
#include <hip/hip_bf16.h>

// out[i0,i2,i1] = sum_r f0[i0,r]*f2[i2,r]*f1[i1,r]; N0=512,N1=512,N2=256,R=32.
// GEMM view: out[p, i1] = G[p,:] . f1[i1,:]^T, G = KR(f0,f2), M=131072, N=512, K=32.
//
// R6: DIAGNOSTIC ROUND (2 internal passes). R4 (LDS-staged stores) and R5
// (direct stores, zero LDS, 2x occupancy) benched within fill-noise of each
// other (293.8 vs 300.7) -> the "kernel = total - 162us fill = ~132us"
// attribution is suspect; dispatch-ordinal spacing shows ~30 tiny reset
// dispatches per iteration that may eat 70-100us. The kernel never appears in
// the top-5 counter rows (all ~162us fills), so run the IDENTICAL R5 body
// twice in one dispatch: Delta(total) = true kernel duration, and if the
// kernel was really ~132us the 2-pass dispatch (~264us) becomes top-1 and we
// finally see its hbm_gbps / FETCH_SIZE / MfmaUtil.
// Pass p remaps blk ^= p<<12 (bijective over 8192 blocks, ~128MB away) so
// pass-2 stores hit cold L2, not pass-1's dirty lines -> honest 2x HBM writes.
// Output written exactly twice globally -> bit-identical, correctness intact.
// Floor: 268 MB fp32 out / 6.5 TB/s (fill-measured) = ~41 us single-pass.

#define N0 512
#define N1 512
#define N2 256
#define R  32

typedef __bf16  bf16x8  __attribute__((ext_vector_type(8)));
typedef float   floatx4 __attribute__((ext_vector_type(4)));

__global__ __launch_bounds__(256, 8)
void cp_mfma_kernel(const float* __restrict__ f0,
                    const float* __restrict__ f1,
                    const float* __restrict__ f2,
                    float* __restrict__ out) {
    const int tid  = threadIdx.x;
    const int wave = tid >> 6;
    const int lane = tid & 63;
    const int n    = lane & 15;   // B: p-col index; A: i1-row index
    const int q    = lane >> 4;   // quad -> k = q*8 + j

    #pragma unroll 1
    for (int pass = 0; pass < 2; ++pass) {
        // Bijective remap: pass 1 handles a block ~128 MB away so its stores
        // don't land in pass-0's still-dirty L2 lines on this CU.
        const int blk     = ((int)blockIdx.x) ^ (pass << 12);
        const int i0      = blk >> 4;
        const int i2_base = (blk & 15) << 4;
        const long p_base = (long)blk * 16;

        // ---- B operand (G fragment): B[k=q*8+j][n] = bf16(f0[i0][k]*f2[i2_base+n][k])
        bf16x8 g;
        {
            const floatx4 v0a = *(const floatx4*)(f0 + i0 * R + q * 8);
            const floatx4 v0b = *(const floatx4*)(f0 + i0 * R + q * 8 + 4);
            const floatx4 v2a = *(const floatx4*)(f2 + (i2_base + n) * R + q * 8);
            const floatx4 v2b = *(const floatx4*)(f2 + (i2_base + n) * R + q * 8 + 4);
            #pragma unroll
            for (int j = 0; j < 4; ++j) {
                g[j]     = (__bf16)(v0a[j] * v2a[j]);
                g[j + 4] = (__bf16)(v0b[j] * v2b[j]);
            }
        }

        // ---- wave covers i1 cols [wave*128, +128): 8 MFMAs, store direct from acc.
        const int colbase = wave * 128;
        float* const outp = out + (p_base + n) * (long)N1 + colbase + q * 4;

        #pragma unroll
        for (int t = 0; t < 8; ++t) {
            // A operand (f1 fragment): A[m=n][k=q*8+j] = bf16(f1[colbase+t*16+m][k])
            const float* f1p = f1 + (colbase + t * 16 + n) * R + q * 8;
            const floatx4 ba = *(const floatx4*)(f1p);
            const floatx4 bb = *(const floatx4*)(f1p + 4);
            bf16x8 a;
            #pragma unroll
            for (int j = 0; j < 4; ++j) {
                a[j]     = (__bf16)ba[j];
                a[j + 4] = (__bf16)bb[j];
            }
            floatx4 c = {0.f, 0.f, 0.f, 0.f};
            const floatx4 d = __builtin_amdgcn_mfma_f32_16x16x32_bf16(a, g, c, 0, 0, 0);
            *(floatx4*)(outp + t * 16) = d;
        }

        // Keep pass-0 stores observable (defeat dead-store elim / cross-pass CSE).
        __asm__ __volatile__("" ::: "memory");
    }
}

extern "C" void kernel_launch(void* const* d_in, const int* in_sizes, int n_in,
                              void* d_out, int out_size, void* d_ws, size_t ws_size,
                              hipStream_t stream) {
    const float* f0 = (const float*)d_in[0];
    const float* f1 = (const float*)d_in[1];
    const float* f2 = (const float*)d_in[2];
    float* out = (float*)d_out;

    const int n_blocks = (N0 * N2) / 16;  // 8192 blocks x 256 threads
    cp_mfma_kernel<<<dim3(n_blocks), dim3(256), 0, stream>>>(f0, f1, f2, out);
}

// Round 3
// 309.716 us; speedup vs baseline: 1.1764x; 1.1764x over previous
//
#include <hip/hip_runtime.h>
#include <hip/hip_bf16.h>

// out[i0,i2,i1] = sum_r f0[i0,r]*f2[i2,r]*f1[i1,r]; N0=512,N1=512,N2=256,R=32.
// GEMM view: out[p, i1] = G[p,:] . f1[i1,:]^T, G = KR(f0,f2), M=131072, N=512, K=32.
//
// R7: single-pass (revert R6 diagnostic) + NON-TEMPORAL stores.
// R6 differencing established the true kernel duration: ~58-60 us/pass
// (Delta 63.7 us at 5%-slower clocks), i.e. 268 MB at ~4.7 TB/s = ~75% of the
// 6.2-6.6 TB/s the harness's own fill achieves on this buffer. Bench total
// (~295 us) = ~162 us poison fill + ~75 us tiny resets + ~60 us kernel.
// Compute floors are negligible (VMEM issue ~1.6 us, VALU ~4 us, MFMA ~0.5 us)
// -> the store stream is everything. R4 (LDS-coalesced 1KB/wave stores) == R5
// (direct 64B-chunk stores) within noise, so the remaining lever is the L2
// write path: output is written once and never read, so stream it past L2
// with nontemporal stores instead of dirtying 268 MB through a 32 MB L2.
// Bit-identical output; absmax stays 0.25.
// Floor: 268 MB / 6.5 TB/s = ~41 us kernel; bench floor ~= 278 us.

#define N0 512
#define N1 512
#define N2 256
#define R  32

typedef __bf16  bf16x8  __attribute__((ext_vector_type(8)));
typedef float   floatx4 __attribute__((ext_vector_type(4)));

__global__ __launch_bounds__(256, 8)
void cp_mfma_kernel(const float* __restrict__ f0,
                    const float* __restrict__ f1,
                    const float* __restrict__ f2,
                    float* __restrict__ out) {
    const int tid  = threadIdx.x;
    const int wave = tid >> 6;
    const int lane = tid & 63;
    const int n    = lane & 15;   // B: p-col index; A: i1-row index
    const int q    = lane >> 4;   // quad -> k = q*8 + j

    const int blk     = blockIdx.x;
    const int i0      = blk >> 4;
    const int i2_base = (blk & 15) << 4;
    const long p_base = (long)blk * 16;

    // ---- B operand (G fragment): B[k=q*8+j][n] = bf16( f0[i0][k] * f2[i2_base+n][k] )
    bf16x8 g;
    {
        const floatx4 v0a = *(const floatx4*)(f0 + i0 * R + q * 8);
        const floatx4 v0b = *(const floatx4*)(f0 + i0 * R + q * 8 + 4);
        const floatx4 v2a = *(const floatx4*)(f2 + (i2_base + n) * R + q * 8);
        const floatx4 v2b = *(const floatx4*)(f2 + (i2_base + n) * R + q * 8 + 4);
        #pragma unroll
        for (int j = 0; j < 4; ++j) {
            g[j]     = (__bf16)(v0a[j] * v2a[j]);
            g[j + 4] = (__bf16)(v0b[j] * v2b[j]);
        }
    }

    // ---- wave covers i1 cols [wave*128, +128): 8 MFMAs, NT-store direct from acc.
    // Lane (n,q) owns out[(p_base+n)][colbase + t*16 + q*4 .. +3]; q groups are
    // 16B-contiguous -> 64B chunks/row/instr; t,t+1 fill the two halves of each
    // 128B line back-to-back.
    const int colbase = wave * 128;
    float* const outp = out + (p_base + n) * (long)N1 + colbase + q * 4;

    #pragma unroll
    for (int t = 0; t < 8; ++t) {
        // A operand (f1 fragment): A[m=n][k=q*8+j] = bf16( f1[colbase+t*16+m][k] )
        const float* f1p = f1 + (colbase + t * 16 + n) * R + q * 8;
        const floatx4 ba = *(const floatx4*)(f1p);
        const floatx4 bb = *(const floatx4*)(f1p + 4);
        bf16x8 a;
        #pragma unroll
        for (int j = 0; j < 4; ++j) {
            a[j]     = (__bf16)ba[j];
            a[j + 4] = (__bf16)bb[j];
        }
        floatx4 c = {0.f, 0.f, 0.f, 0.f};
        // Swapped operands: D[m=i1_local][n=p_col] (layout m89-verified).
        const floatx4 d = __builtin_amdgcn_mfma_f32_16x16x32_bf16(a, g, c, 0, 0, 0);
        // Output is write-once / never re-read: stream past L2 (nt).
        __builtin_nontemporal_store(d, (floatx4*)(outp + t * 16));
    }
}

extern "C" void kernel_launch(void* const* d_in, const int* in_sizes, int n_in,
                              void* d_out, int out_size, void* d_ws, size_t ws_size,
                              hipStream_t stream) {
    const float* f0 = (const float*)d_in[0];
    const float* f1 = (const float*)d_in[1];
    const float* f2 = (const float*)d_in[2];
    float* out = (float*)d_out;

    const int n_blocks = (N0 * N2) / 16;  // 8192 blocks x 256 threads
    cp_mfma_kernel<<<dim3(n_blocks), dim3(256), 0, stream>>>(f0, f1, f2, out);
}

// Round 4
// 300.421 us; speedup vs baseline: 1.2128x; 1.0309x over previous
//
#include <hip/hip_runtime.h>
#include <hip/hip_bf16.h>

// out[i0,i2,i1] = sum_r f0[i0,r]*f2[i2,r]*f1[i1,r]; N0=512,N1=512,N2=256,R=32.
// GEMM view: out[p, i1] = G[p,:] . f1[i1,:]^T, G = KR(f0,f2), M=131072, N=512, K=32.
//
// R8 FINAL: plain direct stores (revert R7's nontemporal — clock-normalized
// neutral-to-harmful; pre-committed matrix says revert).
// Session ledger:
//   R4  LDS-staged coalesced stores        293.8 us total
//   R5  direct stores, zero LDS (this)     300.7 us total
//   R6  2-pass diagnostic: TRUE KERNEL ~58-60 us (268 MB @ ~4.7 TB/s, 72% of
//       the 6.4 TB/s the harness's own 1 GB poison fill hits on this buffer)
//   R7  NT stores                          309.7 us (fills 3us/ea slower; ~306 norm)
// Bench anatomy: ~162 us poison fill + ~75 us of ~30 tiny reset dispatches +
// ~60 us kernel. All three store-path variants (LDS full-line / direct 64B /
// NT) measure identical within the +-8 us harness noise -> store pattern is
// not the residual; remaining ~15 us over the pure-fill floor is the mixed
// read+MFMA+write stream. Compute floors: VMEM issue ~0.5 us, VALU ~4 us,
// MFMA ~0.5 us. Kernel is within 1.3x of a pure-write-hardware floor and
// every structural lever A/B'd to null -> roofline.
//
// Fragment layouts (verified): A and B of mfma_f32_16x16x32_bf16 share the
// per-lane layout row=lane&15, k=(lane>>4)*8+j (R2==R3 bit-identical proof);
// D: col=lane&15, row=(lane>>4)*4+v (m89). Operand swap (A=f1, B=G) makes each
// lane's floatx4 = 4 consecutive i1 floats of one output row -> store straight
// from the accumulator: no LDS, no barrier, 48 VGPR, 8 blocks/CU.

#define N0 512
#define N1 512
#define N2 256
#define R  32

typedef __bf16  bf16x8  __attribute__((ext_vector_type(8)));
typedef float   floatx4 __attribute__((ext_vector_type(4)));

__global__ __launch_bounds__(256, 8)
void cp_mfma_kernel(const float* __restrict__ f0,
                    const float* __restrict__ f1,
                    const float* __restrict__ f2,
                    float* __restrict__ out) {
    const int tid  = threadIdx.x;
    const int wave = tid >> 6;
    const int lane = tid & 63;
    const int n    = lane & 15;   // B: p-col index; A: i1-row index
    const int q    = lane >> 4;   // quad -> k = q*8 + j

    const int blk     = blockIdx.x;
    const int i0      = blk >> 4;
    const int i2_base = (blk & 15) << 4;
    const long p_base = (long)blk * 16;

    // ---- B operand (G fragment): B[k=q*8+j][n] = bf16( f0[i0][k] * f2[i2_base+n][k] )
    bf16x8 g;
    {
        const floatx4 v0a = *(const floatx4*)(f0 + i0 * R + q * 8);
        const floatx4 v0b = *(const floatx4*)(f0 + i0 * R + q * 8 + 4);
        const floatx4 v2a = *(const floatx4*)(f2 + (i2_base + n) * R + q * 8);
        const floatx4 v2b = *(const floatx4*)(f2 + (i2_base + n) * R + q * 8 + 4);
        #pragma unroll
        for (int j = 0; j < 4; ++j) {
            g[j]     = (__bf16)(v0a[j] * v2a[j]);
            g[j + 4] = (__bf16)(v0b[j] * v2b[j]);
        }
    }

    // ---- wave covers i1 cols [wave*128, +128): 8 MFMAs, store direct from acc.
    // Lane (n,q) owns out[(p_base+n)][colbase + t*16 + q*4 .. +3]; q groups are
    // 16B-contiguous -> 64B chunks/row/instr; t,t+1 fill the two halves of each
    // 128B line back-to-back.
    const int colbase = wave * 128;
    float* const outp = out + (p_base + n) * (long)N1 + colbase + q * 4;

    #pragma unroll
    for (int t = 0; t < 8; ++t) {
        // A operand (f1 fragment): A[m=n][k=q*8+j] = bf16( f1[colbase+t*16+m][k] )
        const float* f1p = f1 + (colbase + t * 16 + n) * R + q * 8;
        const floatx4 ba = *(const floatx4*)(f1p);
        const floatx4 bb = *(const floatx4*)(f1p + 4);
        bf16x8 a;
        #pragma unroll
        for (int j = 0; j < 4; ++j) {
            a[j]     = (__bf16)ba[j];
            a[j + 4] = (__bf16)bb[j];
        }
        floatx4 c = {0.f, 0.f, 0.f, 0.f};
        // Swapped operands: D[m=i1_local][n=p_col] (layout m89-verified).
        const floatx4 d = __builtin_amdgcn_mfma_f32_16x16x32_bf16(a, g, c, 0, 0, 0);
        *(floatx4*)(outp + t * 16) = d;
    }
}

extern "C" void kernel_launch(void* const* d_in, const int* in_sizes, int n_in,
                              void* d_out, int out_size, void* d_ws, size_t ws_size,
                              hipStream_t stream) {
    const float* f0 = (const float*)d_in[0];
    const float* f1 = (const float*)d_in[1];
    const float* f2 = (const float*)d_in[2];
    float* out = (float*)d_out;

    const int n_blocks = (N0 * N2) / 16;  // 8192 blocks x 256 threads
    cp_mfma_kernel<<<dim3(n_blocks), dim3(256), 0, stream>>>(f0, f1, f2, out);
}